// Round 8
// baseline (73.454 us; speedup 1.0000x reference)
//
#include <hip/hip_runtime.h>

#define BS 2048
#define DIM 256
#define MARGIN_F 0.3f
#define REP 4

typedef __attribute__((ext_vector_type(4))) float f32x4;
typedef __attribute__((ext_vector_type(2))) __fp16 fp16x2;   // cvt_pkrtz return type
typedef __attribute__((ext_vector_type(8))) _Float16 f16x8;  // MFMA operand type

// Async global->LDS direct load, 16 B per lane (global_load_lds_dwordx4).
__device__ __forceinline__ void gload_lds16(const void* g, void* l) {
    __builtin_amdgcn_global_load_lds((const __attribute__((address_space(1))) void*)g,
                                     (__attribute__((address_space(3))) void*)l,
                                     16, 0, 0);
}

// Kernel 1: fused norms + fp32->fp16 pre-convert with PRE-SWIZZLED layout
// (identical to r7, verified absmax 0.0). Also zeroes d_out.
__global__ __launch_bounds__(256) void tl_prep(const float* __restrict__ sketch,
                                               const float* __restrict__ photo,
                                               float* __restrict__ sn,
                                               float* __restrict__ pn,
                                               float* __restrict__ pos,
                                               _Float16* __restrict__ hs,
                                               _Float16* __restrict__ hp,
                                               float* __restrict__ out) {
    const int t = threadIdx.x;
    const int w = t >> 6, lane = t & 63;
    const int row = blockIdx.x * 4 + w;
    const float4 s4 = *reinterpret_cast<const float4*>(&sketch[(size_t)row * DIM + lane * 4]);
    const float4 p4 = *reinterpret_cast<const float4*>(&photo [(size_t)row * DIM + lane * 4]);

    float vs = s4.x * s4.x + s4.y * s4.y + s4.z * s4.z + s4.w * s4.w;
    float vp = p4.x * p4.x + p4.y * p4.y + p4.z * p4.z + p4.w * p4.w;
    float dx = s4.x - p4.x, dy = s4.y - p4.y, dz = s4.z - p4.z, dw = s4.w - p4.w;
    float vd = dx * dx + dy * dy + dz * dz + dw * dw;
    #pragma unroll
    for (int off = 32; off > 0; off >>= 1) {
        vs += __shfl_down(vs, off);
        vp += __shfl_down(vp, off);
        vd += __shfl_down(vd, off);
    }
    if (lane == 0) { sn[row] = vs; pn[row] = vp; pos[row] = sqrtf(vd); }

    union { fp16x2 h2[2]; uint2 u; } cs, cp;
    cs.h2[0] = __builtin_amdgcn_cvt_pkrtz(s4.x, s4.y);
    cs.h2[1] = __builtin_amdgcn_cvt_pkrtz(s4.z, s4.w);
    cp.h2[0] = __builtin_amdgcn_cvt_pkrtz(p4.x, p4.y);
    cp.h2[1] = __builtin_amdgcn_cvt_pkrtz(p4.z, p4.w);
    const int qg = lane >> 1;
    const int pg = (qg & 24) | ((qg & 7) ^ (row & 7));
    const size_t dsth = (size_t)row * DIM + pg * 8 + (lane & 1) * 4;
    *reinterpret_cast<uint2*>(&hs[dsth]) = cs.u;
    *reinterpret_cast<uint2*>(&hp[dsth]) = cp.u;

    if (blockIdx.x == 0 && t == 0) out[0] = 0.0f;
}

// Kernel 2, DIAGNOSTIC template. Body = r7's gload_lds GEMM, repeated REP x
// with no acc reset (epilogue scales by 1/REP -> same validated scalar).
// V=0 FULL: staging+compute, real output.
// V=1 COMPUTE: stage once, rep {ds_read+MFMA+barriers} only -> LDS/MFMA pipe.
// V=2 STAGE: rep {gload_lds+barriers} only -> async staging path.
template<int V>
__global__ __launch_bounds__(256) void tl_var(const _Float16* __restrict__ hp,
                                              const _Float16* __restrict__ hs,
                                              const float* __restrict__ sn,
                                              const float* __restrict__ pn,
                                              const float* __restrict__ pos,
                                              float* __restrict__ outv) {
    __shared__ _Float16 As[64][64];
    __shared__ _Float16 Bs[64][64];

    const int t = threadIdx.x;
    const int i0 = blockIdx.y * 64;
    const int j0 = blockIdx.x * 64;
    const int w = t >> 6, lane = t & 63;
    const int wr = (w >> 1) * 32;
    const int wc = (w & 1) * 32;
    const int r16 = lane & 15, g = lane >> 4;

    f32x4 acc[2][2] = {};

    const int srow = w * 16 + (lane >> 3);
    const int sch  = lane & 7;
    const _Float16* gA0 = &hp[(size_t)(i0 + srow) * DIM + sch * 8];
    const _Float16* gB0 = &hs[(size_t)(j0 + srow) * DIM + sch * 8];
    const _Float16* gA1 = gA0 + 8 * DIM;
    const _Float16* gB1 = gB0 + 8 * DIM;
    _Float16* lA0 = &As[w * 16][0];
    _Float16* lA1 = &As[w * 16 + 8][0];
    _Float16* lB0 = &Bs[w * 16][0];
    _Float16* lB1 = &Bs[w * 16 + 8][0];

    if (V == 1) {   // stage one window once; reps re-read it
        gload_lds16(gA0, lA0); gload_lds16(gA1, lA1);
        gload_lds16(gB0, lB0); gload_lds16(gB1, lB1);
        __syncthreads();
    }

    for (int rep = 0; rep < REP; ++rep) {
        for (int kw = 0; kw < 4; ++kw) {
            if (V != 1) {
                const int koff = kw * 64;
                gload_lds16(gA0 + koff, lA0);
                gload_lds16(gA1 + koff, lA1);
                gload_lds16(gB0 + koff, lB0);
                gload_lds16(gB1 + koff, lB1);
            }
            __syncthreads();
            if (V != 2) {
                #pragma unroll
                for (int ks = 0; ks < 2; ++ks) {
                    const int q = ks * 4 + g;
                    f16x8 af[2], bf[2];
                    #pragma unroll
                    for (int m = 0; m < 2; ++m) {
                        const int r = wr + m * 16 + r16;
                        af[m] = *reinterpret_cast<const f16x8*>(&As[r][(q ^ (r16 & 7)) * 8]);
                    }
                    #pragma unroll
                    for (int n = 0; n < 2; ++n) {
                        const int r = wc + n * 16 + r16;
                        bf[n] = *reinterpret_cast<const f16x8*>(&Bs[r][(q ^ (r16 & 7)) * 8]);
                    }
                    #pragma unroll
                    for (int m = 0; m < 2; ++m)
                        #pragma unroll
                        for (int n = 0; n < 2; ++n)
                            acc[m][n] = __builtin_amdgcn_mfma_f32_16x16x32_f16(af[m], bf[n], acc[m][n], 0, 0, 0);
                }
            }
            __syncthreads();
        }
    }

    // Epilogue (verified layout). acc holds REP x the true cross term.
    const float invrep = 1.0f / (float)REP;
    const int jl = r16;
    const int rl = g * 4;

    float partial = 0.0f;
    #pragma unroll
    for (int n = 0; n < 2; ++n) {
        const int j = j0 + wc + n * 16 + jl;
        const float snj = sn[j];
        const float posj = pos[j];
        #pragma unroll
        for (int m = 0; m < 2; ++m) {
            const int ibase = i0 + wr + m * 16 + rl;
            #pragma unroll
            for (int r = 0; r < 4; ++r) {
                const int i = ibase + r;
                const float c = acc[m][n][r] * invrep;
                float neg2 = fmaxf(pn[i] + snj - 2.0f * c, 0.0f);
                float tl = posj - sqrtf(neg2) + MARGIN_F;
                partial += (i != j) ? fmaxf(tl, 0.0f) : 0.0f;
            }
        }
    }

    #pragma unroll
    for (int off = 32; off > 0; off >>= 1) partial += __shfl_down(partial, off);
    __shared__ float lsum[4];
    if (lane == 0) lsum[w] = partial;
    __syncthreads();
    if (t == 0) {
        float s = lsum[0] + lsum[1] + lsum[2] + lsum[3];
        atomicAdd(outv, s * (1.0f / ((float)BS * (float)BS)));
    }
}

extern "C" void kernel_launch(void* const* d_in, const int* in_sizes, int n_in,
                              void* d_out, int out_size, void* d_ws, size_t ws_size,
                              hipStream_t stream) {
    const float* sketch = (const float*)d_in[0];
    const float* photo  = (const float*)d_in[1];
    float* out = (float*)d_out;

    float* sn  = (float*)d_ws;            // BS floats
    float* pn  = sn + BS;                 // BS floats
    float* pos = pn + BS;                 // BS floats
    _Float16* hp = (_Float16*)(pos + BS); // BS*DIM halves (photo fp16, swizzled)
    _Float16* hs = hp + (size_t)BS * DIM; // BS*DIM halves (sketch fp16, swizzled)
    float* scratch = (float*)(hs + (size_t)BS * DIM);  // timing-only sink

    tl_prep<<<dim3(BS / 4), dim3(256), 0, stream>>>(sketch, photo, sn, pn, pos, hs, hp, out);

    dim3 grid(BS / 64, BS / 64);   // 32 x 32 = 1024 blocks
    tl_var<0><<<grid, dim3(256), 0, stream>>>(hp, hs, sn, pn, pos, out);      // FULL (real)
    tl_var<1><<<grid, dim3(256), 0, stream>>>(hp, hs, sn, pn, pos, scratch);  // COMPUTE-only
    tl_var<2><<<grid, dim3(256), 0, stream>>>(hp, hs, sn, pn, pos, scratch);  // STAGE-only
}

// Round 9
// 28.753 us; speedup vs baseline: 2.5547x; 2.5547x over previous
//
#include <hip/hip_runtime.h>

#define BS 2048
#define DIM 256
#define MARGIN_F 0.3f

typedef __attribute__((ext_vector_type(4))) float f32x4;
typedef __attribute__((ext_vector_type(2))) __fp16 fp16x2;   // cvt_pkrtz return type
typedef __attribute__((ext_vector_type(8))) _Float16 f16x8;  // MFMA operand type

// Async global->LDS direct load, 16 B per lane (global_load_lds_dwordx4).
__device__ __forceinline__ void gload_lds16(const void* g, void* l) {
    __builtin_amdgcn_global_load_lds((const __attribute__((address_space(1))) void*)g,
                                     (__attribute__((address_space(3))) void*)l,
                                     16, 0, 0);
}

// Kernel 1: fused norms + fp32->fp16 pre-convert with PRE-SWIZZLED layout
// (verbatim r7, verified absmax 0.0). Also zeroes d_out.
__global__ __launch_bounds__(256) void tl_prep(const float* __restrict__ sketch,
                                               const float* __restrict__ photo,
                                               float* __restrict__ sn,
                                               float* __restrict__ pn,
                                               float* __restrict__ pos,
                                               _Float16* __restrict__ hs,
                                               _Float16* __restrict__ hp,
                                               float* __restrict__ out) {
    const int t = threadIdx.x;
    const int w = t >> 6, lane = t & 63;
    const int row = blockIdx.x * 4 + w;
    const float4 s4 = *reinterpret_cast<const float4*>(&sketch[(size_t)row * DIM + lane * 4]);
    const float4 p4 = *reinterpret_cast<const float4*>(&photo [(size_t)row * DIM + lane * 4]);

    float vs = s4.x * s4.x + s4.y * s4.y + s4.z * s4.z + s4.w * s4.w;
    float vp = p4.x * p4.x + p4.y * p4.y + p4.z * p4.z + p4.w * p4.w;
    float dx = s4.x - p4.x, dy = s4.y - p4.y, dz = s4.z - p4.z, dw = s4.w - p4.w;
    float vd = dx * dx + dy * dy + dz * dz + dw * dw;
    #pragma unroll
    for (int off = 32; off > 0; off >>= 1) {
        vs += __shfl_down(vs, off);
        vp += __shfl_down(vp, off);
        vd += __shfl_down(vd, off);
    }
    if (lane == 0) { sn[row] = vs; pn[row] = vp; pos[row] = sqrtf(vd); }

    union { fp16x2 h2[2]; uint2 u; } cs, cp;
    cs.h2[0] = __builtin_amdgcn_cvt_pkrtz(s4.x, s4.y);
    cs.h2[1] = __builtin_amdgcn_cvt_pkrtz(s4.z, s4.w);
    cp.h2[0] = __builtin_amdgcn_cvt_pkrtz(p4.x, p4.y);
    cp.h2[1] = __builtin_amdgcn_cvt_pkrtz(p4.z, p4.w);
    const int qg = lane >> 1;
    const int pg = (qg & 24) | ((qg & 7) ^ (row & 7));
    const size_t dsth = (size_t)row * DIM + pg * 8 + (lane & 1) * 4;
    *reinterpret_cast<uint2*>(&hs[dsth]) = cs.u;
    *reinterpret_cast<uint2*>(&hp[dsth]) = cp.u;

    if (blockIdx.x == 0 && t == 0) out[0] = 0.0f;
}

// Kernel 2: r7's gload_lds MFMA GEMM, recompiled for MINIMAL CODE SIZE.
// kw / ks loops forced rolled (#pragma unroll 1); fragment and accumulator
// registers statically named so nothing needs dynamic register indexing.
__global__ __launch_bounds__(256) void tl_gemm(const _Float16* __restrict__ hp,
                                               const _Float16* __restrict__ hs,
                                               const float* __restrict__ sn,
                                               const float* __restrict__ pn,
                                               const float* __restrict__ pos,
                                               float* __restrict__ out) {
    __shared__ _Float16 As[64][64];
    __shared__ _Float16 Bs[64][64];

    const int t = threadIdx.x;
    const int i0 = blockIdx.y * 64;
    const int j0 = blockIdx.x * 64;
    const int w = t >> 6, lane = t & 63;
    const int wr = (w >> 1) * 32;
    const int wc = (w & 1) * 32;
    const int r16 = lane & 15, g = lane >> 4;

    f32x4 acc00 = {}, acc01 = {}, acc10 = {}, acc11 = {};

    const int srow = w * 16 + (lane >> 3);
    const int sch  = lane & 7;
    const _Float16* gA0 = &hp[(size_t)(i0 + srow) * DIM + sch * 8];
    const _Float16* gB0 = &hs[(size_t)(j0 + srow) * DIM + sch * 8];
    const _Float16* gA1 = gA0 + 8 * DIM;
    const _Float16* gB1 = gB0 + 8 * DIM;
    _Float16* lA0 = &As[w * 16][0];
    _Float16* lA1 = &As[w * 16 + 8][0];
    _Float16* lB0 = &Bs[w * 16][0];
    _Float16* lB1 = &Bs[w * 16 + 8][0];

    // Deswizzle XOR per fragment row (row&7 == r16&7 since wr, +16 are mult of 8)
    const int xa = (r16 & 7);
    const _Float16* rA0 = &As[wr + r16][0];
    const _Float16* rA1 = &As[wr + 16 + r16][0];
    const _Float16* rB0 = &Bs[wc + r16][0];
    const _Float16* rB1 = &Bs[wc + 16 + r16][0];

    #pragma unroll 1
    for (int kw = 0; kw < 4; ++kw) {
        const int koff = kw * 64;
        gload_lds16(gA0 + koff, lA0);
        gload_lds16(gA1 + koff, lA1);
        gload_lds16(gB0 + koff, lB0);
        gload_lds16(gB1 + koff, lB1);
        __syncthreads();
        #pragma unroll 1
        for (int ks = 0; ks < 2; ++ks) {
            const int q8 = ((ks * 4 + g) ^ xa) * 8;
            f16x8 a0 = *reinterpret_cast<const f16x8*>(rA0 + q8);
            f16x8 a1 = *reinterpret_cast<const f16x8*>(rA1 + q8);
            f16x8 b0 = *reinterpret_cast<const f16x8*>(rB0 + q8);
            f16x8 b1 = *reinterpret_cast<const f16x8*>(rB1 + q8);
            acc00 = __builtin_amdgcn_mfma_f32_16x16x32_f16(a0, b0, acc00, 0, 0, 0);
            acc01 = __builtin_amdgcn_mfma_f32_16x16x32_f16(a0, b1, acc01, 0, 0, 0);
            acc10 = __builtin_amdgcn_mfma_f32_16x16x32_f16(a1, b0, acc10, 0, 0, 0);
            acc11 = __builtin_amdgcn_mfma_f32_16x16x32_f16(a1, b1, acc11, 0, 0, 0);
        }
        __syncthreads();
    }

    // Fused epilogue (verified layout): col = lane&15 (j), row = g*4 + reg (i).
    // Unrolled only where static register indexing requires it.
    const int jl = r16;
    const int rl = g * 4;
    float partial = 0.0f;

    #pragma unroll
    for (int n = 0; n < 2; ++n) {
        const int j = j0 + wc + n * 16 + jl;
        const float snj = sn[j];
        const float posj = pos[j];
        const f32x4 cn0 = (n == 0) ? acc00 : acc01;
        const f32x4 cn1 = (n == 0) ? acc10 : acc11;
        #pragma unroll
        for (int m = 0; m < 2; ++m) {
            const int ibase = i0 + wr + m * 16 + rl;
            const f32x4 cv = (m == 0) ? cn0 : cn1;
            #pragma unroll
            for (int r = 0; r < 4; ++r) {
                const int i = ibase + r;
                const float c = cv[r];
                float neg2 = fmaxf(pn[i] + snj - 2.0f * c, 0.0f);
                float tl = posj - sqrtf(neg2) + MARGIN_F;
                partial += (i != j) ? fmaxf(tl, 0.0f) : 0.0f;
            }
        }
    }

    #pragma unroll
    for (int off = 32; off > 0; off >>= 1) partial += __shfl_down(partial, off);
    __shared__ float lsum[4];
    if (lane == 0) lsum[w] = partial;
    __syncthreads();
    if (t == 0) {
        float s = lsum[0] + lsum[1] + lsum[2] + lsum[3];
        atomicAdd(out, s * (1.0f / ((float)BS * (float)BS)));
    }
}

extern "C" void kernel_launch(void* const* d_in, const int* in_sizes, int n_in,
                              void* d_out, int out_size, void* d_ws, size_t ws_size,
                              hipStream_t stream) {
    const float* sketch = (const float*)d_in[0];
    const float* photo  = (const float*)d_in[1];
    float* out = (float*)d_out;

    float* sn  = (float*)d_ws;            // BS floats
    float* pn  = sn + BS;                 // BS floats
    float* pos = pn + BS;                 // BS floats
    _Float16* hp = (_Float16*)(pos + BS); // BS*DIM halves (photo fp16, swizzled)
    _Float16* hs = hp + (size_t)BS * DIM; // BS*DIM halves (sketch fp16, swizzled)

    tl_prep<<<dim3(BS / 4), dim3(256), 0, stream>>>(sketch, photo, sn, pn, pos, hs, hp, out);

    dim3 grid(BS / 64, BS / 64);   // 32 x 32 = 1024 blocks
    tl_gemm<<<grid, dim3(256), 0, stream>>>(hp, hs, sn, pn, pos, out);
}

// Round 10
// 18.614 us; speedup vs baseline: 3.9462x; 1.5447x over previous
//
#include <hip/hip_runtime.h>

#define BS 2048
#define DIM 256
#define MARGIN_F 0.3f
#define NBLK 1024   // gemm grid blocks (32x32)

typedef __attribute__((ext_vector_type(4))) float f32x4;
typedef __attribute__((ext_vector_type(2))) __fp16 fp16x2;   // cvt_pkrtz return type
typedef __attribute__((ext_vector_type(8))) _Float16 f16x8;  // MFMA operand type

// Async global->LDS direct load, 16 B per lane (global_load_lds_dwordx4).
__device__ __forceinline__ void gload_lds16(const void* g, void* l) {
    __builtin_amdgcn_global_load_lds((const __attribute__((address_space(1))) void*)g,
                                     (__attribute__((address_space(3))) void*)l,
                                     16, 0, 0);
}

// Kernel 1: fused norms + fp32->fp16 pre-convert with PRE-SWIZZLED layout
// (verbatim r7/r9, verified absmax 0.0).
__global__ __launch_bounds__(256) void tl_prep(const float* __restrict__ sketch,
                                               const float* __restrict__ photo,
                                               float* __restrict__ sn,
                                               float* __restrict__ pn,
                                               float* __restrict__ pos,
                                               _Float16* __restrict__ hs,
                                               _Float16* __restrict__ hp) {
    const int t = threadIdx.x;
    const int w = t >> 6, lane = t & 63;
    const int row = blockIdx.x * 4 + w;
    const float4 s4 = *reinterpret_cast<const float4*>(&sketch[(size_t)row * DIM + lane * 4]);
    const float4 p4 = *reinterpret_cast<const float4*>(&photo [(size_t)row * DIM + lane * 4]);

    float vs = s4.x * s4.x + s4.y * s4.y + s4.z * s4.z + s4.w * s4.w;
    float vp = p4.x * p4.x + p4.y * p4.y + p4.z * p4.z + p4.w * p4.w;
    float dx = s4.x - p4.x, dy = s4.y - p4.y, dz = s4.z - p4.z, dw = s4.w - p4.w;
    float vd = dx * dx + dy * dy + dz * dz + dw * dw;
    #pragma unroll
    for (int off = 32; off > 0; off >>= 1) {
        vs += __shfl_down(vs, off);
        vp += __shfl_down(vp, off);
        vd += __shfl_down(vd, off);
    }
    if (lane == 0) { sn[row] = vs; pn[row] = vp; pos[row] = sqrtf(vd); }

    union { fp16x2 h2[2]; uint2 u; } cs, cp;
    cs.h2[0] = __builtin_amdgcn_cvt_pkrtz(s4.x, s4.y);
    cs.h2[1] = __builtin_amdgcn_cvt_pkrtz(s4.z, s4.w);
    cp.h2[0] = __builtin_amdgcn_cvt_pkrtz(p4.x, p4.y);
    cp.h2[1] = __builtin_amdgcn_cvt_pkrtz(p4.z, p4.w);
    const int qg = lane >> 1;
    const int pg = (qg & 24) | ((qg & 7) ^ (row & 7));
    const size_t dsth = (size_t)row * DIM + pg * 8 + (lane & 1) * 4;
    *reinterpret_cast<uint2*>(&hs[dsth]) = cs.u;
    *reinterpret_cast<uint2*>(&hp[dsth]) = cp.u;
}

// Kernel 2: verbatim r9 gemm EXCEPT the block result is a plain store to
// partials[bid] (NO atomicAdd -- the 1024-deep same-line RMW chain was the
// ~22 us invariant).
__global__ __launch_bounds__(256) void tl_gemm(const _Float16* __restrict__ hp,
                                               const _Float16* __restrict__ hs,
                                               const float* __restrict__ sn,
                                               const float* __restrict__ pn,
                                               const float* __restrict__ pos,
                                               float* __restrict__ partials) {
    __shared__ _Float16 As[64][64];
    __shared__ _Float16 Bs[64][64];

    const int t = threadIdx.x;
    const int i0 = blockIdx.y * 64;
    const int j0 = blockIdx.x * 64;
    const int w = t >> 6, lane = t & 63;
    const int wr = (w >> 1) * 32;
    const int wc = (w & 1) * 32;
    const int r16 = lane & 15, g = lane >> 4;

    f32x4 acc00 = {}, acc01 = {}, acc10 = {}, acc11 = {};

    const int srow = w * 16 + (lane >> 3);
    const int sch  = lane & 7;
    const _Float16* gA0 = &hp[(size_t)(i0 + srow) * DIM + sch * 8];
    const _Float16* gB0 = &hs[(size_t)(j0 + srow) * DIM + sch * 8];
    const _Float16* gA1 = gA0 + 8 * DIM;
    const _Float16* gB1 = gB0 + 8 * DIM;
    _Float16* lA0 = &As[w * 16][0];
    _Float16* lA1 = &As[w * 16 + 8][0];
    _Float16* lB0 = &Bs[w * 16][0];
    _Float16* lB1 = &Bs[w * 16 + 8][0];

    const int xa = (r16 & 7);
    const _Float16* rA0 = &As[wr + r16][0];
    const _Float16* rA1 = &As[wr + 16 + r16][0];
    const _Float16* rB0 = &Bs[wc + r16][0];
    const _Float16* rB1 = &Bs[wc + 16 + r16][0];

    #pragma unroll 1
    for (int kw = 0; kw < 4; ++kw) {
        const int koff = kw * 64;
        gload_lds16(gA0 + koff, lA0);
        gload_lds16(gA1 + koff, lA1);
        gload_lds16(gB0 + koff, lB0);
        gload_lds16(gB1 + koff, lB1);
        __syncthreads();
        #pragma unroll 1
        for (int ks = 0; ks < 2; ++ks) {
            const int q8 = ((ks * 4 + g) ^ xa) * 8;
            f16x8 a0 = *reinterpret_cast<const f16x8*>(rA0 + q8);
            f16x8 a1 = *reinterpret_cast<const f16x8*>(rA1 + q8);
            f16x8 b0 = *reinterpret_cast<const f16x8*>(rB0 + q8);
            f16x8 b1 = *reinterpret_cast<const f16x8*>(rB1 + q8);
            acc00 = __builtin_amdgcn_mfma_f32_16x16x32_f16(a0, b0, acc00, 0, 0, 0);
            acc01 = __builtin_amdgcn_mfma_f32_16x16x32_f16(a0, b1, acc01, 0, 0, 0);
            acc10 = __builtin_amdgcn_mfma_f32_16x16x32_f16(a1, b0, acc10, 0, 0, 0);
            acc11 = __builtin_amdgcn_mfma_f32_16x16x32_f16(a1, b1, acc11, 0, 0, 0);
        }
        __syncthreads();
    }

    // Fused epilogue (verified layout): col = lane&15 (j), row = g*4 + reg (i).
    const int jl = r16;
    const int rl = g * 4;
    float partial = 0.0f;

    #pragma unroll
    for (int n = 0; n < 2; ++n) {
        const int j = j0 + wc + n * 16 + jl;
        const float snj = sn[j];
        const float posj = pos[j];
        const f32x4 cn0 = (n == 0) ? acc00 : acc01;
        const f32x4 cn1 = (n == 0) ? acc10 : acc11;
        #pragma unroll
        for (int m = 0; m < 2; ++m) {
            const int ibase = i0 + wr + m * 16 + rl;
            const f32x4 cv = (m == 0) ? cn0 : cn1;
            #pragma unroll
            for (int r = 0; r < 4; ++r) {
                const int i = ibase + r;
                const float c = cv[r];
                float neg2 = fmaxf(pn[i] + snj - 2.0f * c, 0.0f);
                float tl = posj - sqrtf(neg2) + MARGIN_F;
                partial += (i != j) ? fmaxf(tl, 0.0f) : 0.0f;
            }
        }
    }

    #pragma unroll
    for (int off = 32; off > 0; off >>= 1) partial += __shfl_down(partial, off);
    __shared__ float lsum[4];
    if (lane == 0) lsum[w] = partial;
    __syncthreads();
    if (t == 0)
        partials[blockIdx.y * 32 + blockIdx.x] = lsum[0] + lsum[1] + lsum[2] + lsum[3];
}

// Kernel 3: reduce 1024 block partials -> out[0]. One block, 256 threads,
// float4 loads; every partial slot is rewritten each call (no stale state).
__global__ __launch_bounds__(256) void tl_reduce(const float* __restrict__ partials,
                                                 float* __restrict__ out) {
    const int t = threadIdx.x;
    const float4 v = reinterpret_cast<const float4*>(partials)[t];
    float s = v.x + v.y + v.z + v.w;
    #pragma unroll
    for (int off = 32; off > 0; off >>= 1) s += __shfl_down(s, off);
    __shared__ float lsum[4];
    const int w = t >> 6, lane = t & 63;
    if (lane == 0) lsum[w] = s;
    __syncthreads();
    if (t == 0)
        out[0] = (lsum[0] + lsum[1] + lsum[2] + lsum[3]) * (1.0f / ((float)BS * (float)BS));
}

extern "C" void kernel_launch(void* const* d_in, const int* in_sizes, int n_in,
                              void* d_out, int out_size, void* d_ws, size_t ws_size,
                              hipStream_t stream) {
    const float* sketch = (const float*)d_in[0];
    const float* photo  = (const float*)d_in[1];
    float* out = (float*)d_out;

    float* sn  = (float*)d_ws;              // BS floats
    float* pn  = sn + BS;                   // BS floats
    float* pos = pn + BS;                   // BS floats
    _Float16* hp = (_Float16*)(pos + BS);   // BS*DIM halves (photo fp16, swizzled)
    _Float16* hs = hp + (size_t)BS * DIM;   // BS*DIM halves (sketch fp16, swizzled)
    float* partials = (float*)(hs + (size_t)BS * DIM);  // NBLK floats

    tl_prep<<<dim3(BS / 4), dim3(256), 0, stream>>>(sketch, photo, sn, pn, pos, hs, hp);

    dim3 grid(BS / 64, BS / 64);   // 32 x 32 = 1024 blocks
    tl_gemm<<<grid, dim3(256), 0, stream>>>(hp, hs, sn, pn, pos, partials);

    tl_reduce<<<dim3(1), dim3(256), 0, stream>>>(partials, out);
}